// Round 10
// baseline (230.912 us; speedup 1.0000x reference)
//
#include <hip/hip_runtime.h>

// LIF scan over T=16: mem_t = beta*mem + x_t - spk_{t-1}; spk_t = (mem_t - 1) > 0.
// Neurons independent -> 1 thread owns 16 neurons (4 dense f4 chunks) across all T.
//
// R13: deepen the R/W burst. R12 (barrier-separated R/W regions, 2 planes/pass)
// is the first intervention that WON: lif_kernel fell out of the top-5 slowest
// dispatches (<79.8 us, prev 81-112) and headline hit a session-best 226.9 us.
// Mechanism (DRAM bus-turnaround / row-thrash from fine-grained R/W interleave
// across 32 strided regions) confirmed. Gain partial vs prediction -> burst
// trains still short (8 loads / 8 stores per region). This round: 4 planes per
// pass = 16 loads / 16 stores per unidirectional region, 8 barrier crossings
// instead of 16. Register budget: r[4][4]=64 live across barrier + state 32 +
// addr ~= 110 < 128 (launch_bounds(256,4)) -> no spill.
// Mechanism check: VGPR ~104-124. Null vs R12 -> turnaround lever saturated;
// spill/regression -> revert R12.

constexpr int   T      = 16;
constexpr float BETA   = 0.9f;
constexpr float THRESH = 1.0f;

typedef float f4 __attribute__((ext_vector_type(4)));

__global__ __launch_bounds__(256, 4) void lif_kernel(const float* __restrict__ x,
                                                     float* __restrict__ out,
                                                     int n_per_t) {
    // No FMA contraction: must match numpy's two-rounding fp32 exactly, else
    // ~1-ulp drift flips spikes at the threshold (absmax = 1.0 cascades).
#pragma clang fp contract(off)
    // Block owns 4096 consecutive floats per plane as 4 chunks of 1024;
    // thread owns 4 f4 slots at c*1024 + tid*4. Clamp (not early-return) so
    // every thread reaches the barriers; with n_per_t = 2,097,152 and 512
    // blocks the clamp never engages.
    int base = blockIdx.x * 4096 + threadIdx.x * 4;
    if (base + 3072 + 4 > n_per_t) base = 0;  // degenerate-safe duplicate work

    // Persistent recurrence state, registers only.
    f4 m[4] = {(f4)(0.f), (f4)(0.f), (f4)(0.f), (f4)(0.f)};
    f4 s[4] = {(f4)(0.f), (f4)(0.f), (f4)(0.f), (f4)(0.f)};

    for (int pass = 0; pass < 4; ++pass) {
        const int t0 = pass * 4;

        // READ region: 16 coalesced f4 loads (4 planes x 4 chunks), one
        // unidirectional burst per wave.
        f4 r[4][4];
#pragma unroll
        for (int p = 0; p < 4; ++p) {
            const size_t off = (size_t)(t0 + p) * (size_t)n_per_t + (size_t)base;
#pragma unroll
            for (int c = 0; c < 4; ++c)
                r[p][c] = *reinterpret_cast<const f4*>(x + off + c * 1024);
        }

        // Compute: 4 recurrence steps; results overwrite r.
#pragma unroll
        for (int p = 0; p < 4; ++p) {
#pragma unroll
            for (int c = 0; c < 4; ++c) {
#pragma unroll
                for (int j = 0; j < 4; ++j) {
                    m[c][j] = BETA * m[c][j] + r[p][c][j] - s[c][j] * THRESH;
                    s[c][j] = (m[c][j] - THRESH) > 0.f ? 1.f : 0.f;
                }
                r[p][c] = s[c];
            }
        }

        // Region boundary: stores may not hoist above, loads may not sink below.
        __syncthreads();

        // WRITE region: 16-store unidirectional burst (plain cacheable stores).
#pragma unroll
        for (int p = 0; p < 4; ++p) {
            const size_t off = (size_t)(t0 + p) * (size_t)n_per_t + (size_t)base;
#pragma unroll
            for (int c = 0; c < 4; ++c)
                *reinterpret_cast<f4*>(out + off + c * 1024) = r[p][c];
        }

        // Region boundary: next pass's loads stay after this store burst.
        __syncthreads();
    }
}

extern "C" void kernel_launch(void* const* d_in, const int* in_sizes, int n_in,
                              void* d_out, int out_size, void* d_ws, size_t ws_size,
                              hipStream_t stream) {
    const float* x   = (const float*)d_in[0];
    float*       out = (float*)d_out;

    const int total   = in_sizes[0];      // 33,554,432
    const int n_per_t = total / T;        // 2,097,152 (divisible by 4096)
    const int blocks  = n_per_t / 4096;   // 512 blocks, 256 threads, 16 floats/thread

    lif_kernel<<<dim3(blocks), dim3(256), 0, stream>>>(x, out, n_per_t);
}